// Round 15
// baseline (79.707 us; speedup 1.0000x reference)
//
#include <hip/hip_runtime.h>
#include <hip/hip_bf16.h>

typedef __bf16 bf16_t;
typedef __bf16 bf16x8 __attribute__((ext_vector_type(8)));
typedef float f32x4 __attribute__((ext_vector_type(4)));

#define MFMA(A, B, C) __builtin_amdgcn_mfma_f32_16x16x32_bf16(A, B, C, 0, 0, 0)

// async global->LDS, 16B per lane; LDS dest is wave-uniform base + lane*16.
#define GLL16(g, l) __builtin_amdgcn_global_load_lds(                      \
    (const __attribute__((address_space(1))) void*)(g),                    \
    (__attribute__((address_space(3))) void*)(l), 16, 0, 0)

static __device__ __forceinline__ bf16x8 cvt8p(const float4& a, const float4& b, float sc) {
  bf16x8 o;
  o[0] = (bf16_t)(a.x * sc); o[1] = (bf16_t)(a.y * sc);
  o[2] = (bf16_t)(a.z * sc); o[3] = (bf16_t)(a.w * sc);
  o[4] = (bf16_t)(b.x * sc); o[5] = (bf16_t)(b.y * sc);
  o[6] = (bf16_t)(b.z * sc); o[7] = (bf16_t)(b.w * sc);
  return o;
}

// ---------------- fp32 -> bf16 convert: ACTIVATIONS ONLY --------------------
__global__ __launch_bounds__(256) void cvt_act(
    const float* __restrict__ q, const float* __restrict__ k, const float* __restrict__ v,
    bf16_t* __restrict__ xq, bf16_t* __restrict__ xk, bf16_t* __restrict__ xv)
{
  const long gid = (long)blockIdx.x * 256 + threadIdx.x;
  const float* s; bf16_t* d; long off;
  if (gid < 262144)       { s = q; d = xq; off = gid; }
  else if (gid < 524288)  { s = k; d = xk; off = gid - 262144; }
  else                    { s = v; d = xv; off = gid - 524288; }
  const float* p = s + off * 8;
  float4 a = *(const float4*)p, b = *(const float4*)(p + 4);
  *(bf16x8*)(d + off * 8) = cvt8p(a, b, 1.0f);
}

// ---------------- GEMM core: 128x64 tile, BK=64, NT -------------------------
// R8's exact two-barrier skeleton. A: bf16 via GLL16 staged BEFORE barrier 1
// (trailing barrier makes this race-free, as in R8). W: fp32 reg-staged +
// cvt(sc) + swizzled ds_write into the idle buffer AFTER barrier 1 (idle
// buffer's last readers finished before the previous barrier 2; the ds_writes
// drain at the next barrier 1).
__device__ __forceinline__ void gemm_core(const bf16_t* __restrict__ A,
                                          const float* __restrict__ W, float wsc,
                                          int bm, int bn,
                                          bf16_t (&As)[2][128 * 64],
                                          bf16_t (&Bs)[2][64 * 64],
                                          f32x4 (&acc)[4][2])
{
  const int tid = threadIdx.x, lane = tid & 63, wave = tid >> 6;
  const int l15 = lane & 15, l4 = lane >> 4, l7 = l15 & 7;
  const int wm = (wave >> 1) * 64, wn = (wave & 1) * 32;

  auto stageA = [&](int buf, int k0) {
#pragma unroll
    for (int i = 0; i < 4; ++i) {
      const int id = i * 256 + tid, row = id >> 3, cph = id & 7;
      GLL16(A + (size_t)(bm + row) * 1024 + k0 + 8 * (cph ^ (row & 7)),
            &As[buf][(i * 256 + wave * 64) * 8]);
    }
  };
  float4 rw[2][2];
  auto wload = [&](int k0) {
#pragma unroll
    for (int i = 0; i < 2; ++i) {
      const int id = i * 256 + tid, row = id >> 3, c = id & 7;
      const float* p = W + (size_t)(bn + row) * 1024 + k0 + 8 * c;
      rw[i][0] = *(const float4*)p; rw[i][1] = *(const float4*)(p + 4);
    }
  };
  auto wcommit = [&](int buf) {
#pragma unroll
    for (int i = 0; i < 2; ++i) {
      const int id = i * 256 + tid, row = id >> 3, c = id & 7;
      *(bf16x8*)(&Bs[buf][row * 64 + 8 * (c ^ (row & 7))]) = cvt8p(rw[i][0], rw[i][1], wsc);
    }
  };

  // prologue: A tile 0 via async GLL; W tile 0 regs->cvt->LDS; prefetch W k=64
  wload(0);
  stageA(0, 0);
  wcommit(0);
  wload(64);
#pragma unroll
  for (int s = 0; s < 16; ++s) {
    if (s + 1 < 16) stageA((s + 1) & 1, (s + 1) * 64);   // R8 position
    __syncthreads();                      // barrier 1: As staged, Bs writes drained
    if (s + 1 < 16) {
      wcommit((s + 1) & 1);               // idle buffer; safe after barrier 1
      if (s + 2 < 16) wload((s + 2) * 64);
    }
    const bf16_t* as = As[s & 1];
    const bf16_t* bs = Bs[s & 1];
#pragma unroll
    for (int ks = 0; ks < 2; ++ks) {
      bf16x8 af[4], bfr[2];
#pragma unroll
      for (int i = 0; i < 4; ++i)
        af[i] = *(const bf16x8*)(&as[(wm + i * 16 + l15) * 64 + 8 * ((ks * 4 + l4) ^ l7)]);
#pragma unroll
      for (int j = 0; j < 2; ++j)
        bfr[j] = *(const bf16x8*)(&bs[(wn + j * 16 + l15) * 64 + 8 * ((ks * 4 + l4) ^ l7)]);
#pragma unroll
      for (int i = 0; i < 4; ++i)
#pragma unroll
        for (int j = 0; j < 2; ++j)
          acc[i][j] = MFMA(af[i], bfr[j], acc[i][j]);
    }
    __syncthreads();                      // barrier 2: reads done before re-stage
  }
}

// Wq scaled 1/8; Wk scaled 1/8*log2(e) (attention uses exp2); Wv unscaled.
__global__ __launch_bounds__(256) void gemm_qkv(
    const bf16_t* __restrict__ xq, const bf16_t* __restrict__ xk, const bf16_t* __restrict__ xv,
    const float* __restrict__ Wq, const float* __restrict__ Wk, const float* __restrict__ Wv,
    bf16_t* __restrict__ qo, bf16_t* __restrict__ ko, bf16_t* __restrict__ vt)
{
  __shared__ __align__(16) bf16_t As[2][128 * 64];
  __shared__ __align__(16) bf16_t Bs[2][64 * 64];
  const int z = blockIdx.z;
  const bf16_t* A = z == 0 ? xq : z == 1 ? xk : xv;
  const float* W = z == 0 ? Wq : z == 1 ? Wk : Wv;
  const float wsc = z == 0 ? 0.125f : z == 1 ? 0.125f * 1.44269504f : 1.0f;
  const int bm = blockIdx.x * 128, bn = blockIdx.y * 64;
  f32x4 acc[4][2] = {};
  gemm_core(A, W, wsc, bm, bn, As, Bs, acc);
  const int tid = threadIdx.x, lane = tid & 63, wave = tid >> 6;
  const int l15 = lane & 15, l4 = lane >> 4;
  const int wm = (wave >> 1) * 64, wn = (wave & 1) * 32;
  if (z < 2) {
    bf16_t* C = z == 0 ? qo : ko;
#pragma unroll
    for (int i = 0; i < 4; ++i)
#pragma unroll
      for (int j = 0; j < 2; ++j)
#pragma unroll
        for (int r = 0; r < 4; ++r)
          C[(size_t)(bm + wm + i * 16 + 4 * l4 + r) * 1024 + bn + wn + j * 16 + l15] =
              (bf16_t)acc[i][j][r];
  } else {
#pragma unroll
    for (int i = 0; i < 4; ++i)
#pragma unroll
      for (int j = 0; j < 2; ++j)
#pragma unroll
        for (int r = 0; r < 4; ++r)
          vt[(size_t)(bn + wn + j * 16 + l15) * 2048 + bm + wm + i * 16 + 4 * l4 + r] =
              (bf16_t)acc[i][j][r];
  }
}

__global__ __launch_bounds__(256) void gemm_out(
    const bf16_t* __restrict__ ctx, const float* __restrict__ Wo, float* __restrict__ out)
{
  __shared__ __align__(16) bf16_t As[2][128 * 64];
  __shared__ __align__(16) bf16_t Bs[2][64 * 64];
  const int bm = blockIdx.x * 128, bn = blockIdx.y * 64;
  f32x4 acc[4][2] = {};
  gemm_core(ctx, Wo, 1.0f, bm, bn, As, Bs, acc);
  const int tid = threadIdx.x, lane = tid & 63, wave = tid >> 6;
  const int l15 = lane & 15, l4 = lane >> 4;
  const int wm = (wave >> 1) * 64, wn = (wave & 1) * 32;
#pragma unroll
  for (int i = 0; i < 4; ++i)
#pragma unroll
    for (int j = 0; j < 2; ++j)
#pragma unroll
      for (int r = 0; r < 4; ++r)
        out[(size_t)(bm + wm + i * 16 + 4 * l4 + r) * 1024 + bn + wn + j * 16 + l15] =
            acc[i][j][r];
}

// ---------------- attention: R8's attn1024 + exp2 + setprio -----------------
__global__ __launch_bounds__(1024) void attn1024(
    const bf16_t* __restrict__ Qb, const bf16_t* __restrict__ Kb,
    const bf16_t* __restrict__ Vt, bf16_t* __restrict__ Ctx)
{
  __shared__ __align__(16) char pool[64 * 1024 + 16 * 16 * 40 * 2 + 3 * 64 * 4];
  bf16_t* KsP = (bf16_t*)pool;                       // [2][128*64] swizzled
  bf16_t* VsP = (bf16_t*)(pool + 32 * 1024);         // [2][64*128] swizzled
  bf16_t* PsP = (bf16_t*)(pool + 64 * 1024);         // [16][16*40]
  float*  Osc = (float*)pool;                        // [3][64][66] combine
  float*  Dsc = (float*)(pool + 64 * 1024 + 16 * 16 * 40 * 2);  // [3][64]

  const int bid = blockIdx.x;
  const int h = 2 * (bid & 7) + (bid >> 7);          // head; 2 heads per XCD
  const int jp = (bid >> 3) & 15;
  const int hoff = h * 64;
  const int tid = threadIdx.x, lane = tid & 63, wave = tid >> 6;   // wave 0..15
  const int qg = wave & 3, kh = wave >> 2;           // q-group, key-quarter
  const int l15 = lane & 15, l4 = lane >> 4, l7 = l15 & 7;

  const int qtA = jp, qtB = 31 - jp;
  const int qbA = qtA * 64, qbB = qtB * 64;
  const int nscB = qtB / 2 + 1;                      // block-uniform loop count
  const int qmaxA = qbA + 16 * qg + 15;
  const int qmaxB = qbB + 16 * qg + 15;

  bf16x8 qA[2], qB[2];
#pragma unroll
  for (int kc = 0; kc < 2; ++kc) {
    qA[kc] = *(const bf16x8*)(Qb + (size_t)(qbA + 16 * qg + l15) * 1024 + hoff + 32 * kc + 8 * l4);
    qB[kc] = *(const bf16x8*)(Qb + (size_t)(qbB + 16 * qg + l15) * 1024 + hoff + 32 * kc + 8 * l4);
  }

  f32x4 oA[4] = {}, oB[4] = {};
  float dA[4] = {0.f, 0.f, 0.f, 0.f}, dB[4] = {0.f, 0.f, 0.f, 0.f};

  bf16x8 rk, rv;                                     // 1 K + 1 V chunk per thread
  auto issue = [&](int sc) {
    const int t0 = sc * 128;
    const int kr = tid >> 3, kc = tid & 7;
    rk = *(const bf16x8*)(Kb + (size_t)(t0 + kr) * 1024 + hoff + 8 * kc);
    const int vr = tid >> 4, vc = tid & 15;
    rv = *(const bf16x8*)(Vt + (size_t)(hoff + vr) * 2048 + t0 + 8 * vc);
  };
  auto commit = [&](int buf) {
    const int kr = tid >> 3, kc = tid & 7;
    *(bf16x8*)(&KsP[buf * 8192 + kr * 64 + 8 * (kc ^ (kr & 7))]) = rk;
    const int vr = tid >> 4, vc = tid & 15;
    *(bf16x8*)(&VsP[buf * 8192 + vr * 128 + 8 * (vc ^ (vr & 7))]) = rv;
  };

  bf16_t* Pw = &PsP[wave * 640];
  auto PROC1 = [&](int cur, int sc, int qb, int qmax, const bf16x8 (&qf)[2],
                   f32x4 (&oacc)[4], float (&den)[4]) {
    const int tb = sc * 128 + kh * 32;
    if (tb > qmax) return;                           // wave-uniform skip
    const bf16_t* Ksb = KsP + cur * 8192;
    const bf16_t* Vsb = VsP + cur * 8192;
    f32x4 sv[2] = {};
#pragma unroll
    for (int tf = 0; tf < 2; ++tf) {
      const int krow = 32 * kh + 16 * tf + l15;
      bf16x8 kf0 = *(const bf16x8*)(&Ksb[krow * 64 + 8 * (l4 ^ l7)]);
      bf16x8 kf1 = *(const bf16x8*)(&Ksb[krow * 64 + 8 * ((4 + l4) ^ l7)]);
      __builtin_amdgcn_s_setprio(1);
      sv[tf] = MFMA(qf[0], kf0, sv[tf]);
      sv[tf] = MFMA(qf[1], kf1, sv[tf]);
      __builtin_amdgcn_s_setprio(0);
    }
#pragma unroll
    for (int tf = 0; tf < 2; ++tf) {
      const int t = tb + 16 * tf + l15;
#pragma unroll
      for (int r = 0; r < 4; ++r) {
        const int qq = qb + 16 * qg + 4 * l4 + r;
        const float p = (t <= qq) ? __builtin_amdgcn_exp2f(sv[tf][r]) : 0.0f;
        const bf16_t pb = (bf16_t)p;
        den[r] += (float)pb;
        Pw[(4 * l4 + r) * 40 + 16 * tf + l15] = pb;
      }
    }
    asm volatile("s_waitcnt lgkmcnt(0)" ::: "memory");  // own-wave P visible
    bf16x8 pa = *(const bf16x8*)(&Pw[l15 * 40 + 8 * l4]);
    __builtin_amdgcn_s_setprio(1);
#pragma unroll
    for (int df = 0; df < 4; ++df) {
      const int vrow = 16 * df + l15;
      bf16x8 vf = *(const bf16x8*)(&Vsb[vrow * 128 + 8 * ((4 * kh + l4) ^ l7)]);
      oacc[df] = MFMA(pa, vf, oacc[df]);
    }
    __builtin_amdgcn_s_setprio(0);
  };

  issue(0);
  commit(0);
  int cur = 0;
  for (int sc = 0; sc < nscB; ++sc) {
    const bool pre = (sc + 1 < nscB);
    if (pre) issue(sc + 1);            // loads in flight across the barrier
    __syncthreads();                   // buf[cur] staged for all waves
    PROC1(cur, sc, qbB, qmaxB, qB, oB, dB);
    PROC1(cur, sc, qbA, qmaxA, qA, oA, dA);
    if (pre) commit(cur ^ 1);
    cur ^= 1;
  }

#pragma unroll
  for (int r = 0; r < 4; ++r)
#pragma unroll
    for (int m = 1; m < 16; m <<= 1) {
      dA[r] += __shfl_xor(dA[r], m, 64);
      dB[r] += __shfl_xor(dB[r], m, 64);
    }

  auto combine = [&](int qb, f32x4 (&oacc)[4], float (&den)[4]) {
    __syncthreads();                   // staging/scratch free for reuse
    if (kh > 0) {
      const int rl = qg * 16 + 4 * l4;
#pragma unroll
      for (int r = 0; r < 4; ++r) {
#pragma unroll
        for (int df = 0; df < 4; ++df)
          Osc[((kh - 1) * 64 + rl + r) * 66 + 16 * df + l15] = oacc[df][r];
        if (l15 == 0) Dsc[(kh - 1) * 64 + rl + r] = den[r];
      }
    }
    __syncthreads();
    if (kh == 0) {
#pragma unroll
      for (int r = 0; r < 4; ++r) {
        const int row = qg * 16 + 4 * l4 + r;
        const float dt = den[r] + Dsc[row] + Dsc[64 + row] + Dsc[128 + row];
        const float inv = 1.0f / dt;
#pragma unroll
        for (int df = 0; df < 4; ++df) {
          const int col = 16 * df + l15;
          const float s = oacc[df][r] + Osc[row * 66 + col] +
                          Osc[(64 + row) * 66 + col] + Osc[(128 + row) * 66 + col];
          Ctx[(size_t)(qb + row) * 1024 + hoff + col] = (bf16_t)(s * inv);
        }
      }
    }
  };
  combine(qbA, oA, dA);
  combine(qbB, oB, dB);
}

extern "C" void kernel_launch(void* const* d_in, const int* in_sizes, int n_in,
                              void* d_out, int out_size, void* d_ws, size_t ws_size,
                              hipStream_t stream)
{
  const float* query = (const float*)d_in[0];
  const float* key_  = (const float*)d_in[1];
  const float* value = (const float*)d_in[2];
  // d_in[3] = mask: exactly causal tril, reproduced from indices
  const float* Wq = (const float*)d_in[4];
  const float* Wk = (const float*)d_in[5];
  const float* Wv = (const float*)d_in[6];
  const float* Wo = (const float*)d_in[7];
  float* out = (float*)d_out;

  const size_t SE = (size_t)2048 * 1024;
  bf16_t* xq  = (bf16_t*)d_ws;      // converted activations (bf16)
  bf16_t* xk  = xq + SE;
  bf16_t* xv  = xk + SE;
  bf16_t* qo  = xv + SE;            // projections
  bf16_t* ko  = qo + SE;            // (pre-scaled: q by 1/8, k by log2e/8)
  bf16_t* vt  = ko + SE;            // V transposed [1024][2048]
  bf16_t* ctx = vt + SE;            // attention output

  cvt_act<<<3072, 256, 0, stream>>>(query, key_, value, xq, xk, xv);
  gemm_qkv<<<dim3(16, 16, 3), 256, 0, stream>>>(xq, xk, xv, Wq, Wk, Wv, qo, ko, vt);
  attn1024<<<256, 1024, 0, stream>>>(qo, ko, vt, ctx);
  gemm_out<<<dim3(16, 16), 256, 0, stream>>>(ctx, Wo, out);
}

// Round 16
// 71.632 us; speedup vs baseline: 1.1127x; 1.1127x over previous
//
#include <hip/hip_runtime.h>
#include <hip/hip_bf16.h>

typedef __bf16 bf16_t;
typedef __bf16 bf16x8 __attribute__((ext_vector_type(8)));
typedef float f32x4 __attribute__((ext_vector_type(4)));

#define MFMA(A, B, C) __builtin_amdgcn_mfma_f32_16x16x32_bf16(A, B, C, 0, 0, 0)

// async global->LDS, 16B per lane; LDS dest is wave-uniform base + lane*16.
#define GLL16(g, l) __builtin_amdgcn_global_load_lds(                      \
    (const __attribute__((address_space(1))) void*)(g),                    \
    (__attribute__((address_space(3))) void*)(l), 16, 0, 0)

// ---------------- fused fp32 -> bf16 convert (3 activations + 4 weights) ----
// Wq,Wk pre-scaled 1/sqrt(d); Wk additionally by log2(e) so attn uses exp2.
__global__ __launch_bounds__(256) void cvt_all(
    const float* __restrict__ q, const float* __restrict__ k, const float* __restrict__ v,
    const float* __restrict__ wq, const float* __restrict__ wk,
    const float* __restrict__ wv, const float* __restrict__ wo,
    bf16_t* __restrict__ xq, bf16_t* __restrict__ xk, bf16_t* __restrict__ xv,
    bf16_t* __restrict__ ywq, bf16_t* __restrict__ ywk,
    bf16_t* __restrict__ ywv, bf16_t* __restrict__ ywo)
{
  const long gid = (long)blockIdx.x * 256 + threadIdx.x;
  const float* s; bf16_t* d; long off; float sc = 1.0f;
  if (gid < 262144)       { s = q;  d = xq;  off = gid; }
  else if (gid < 524288)  { s = k;  d = xk;  off = gid - 262144; }
  else if (gid < 786432)  { s = v;  d = xv;  off = gid - 524288; }
  else if (gid < 917504)  { s = wq; d = ywq; off = gid - 786432;  sc = 0.125f; }
  else if (gid < 1048576) { s = wk; d = ywk; off = gid - 917504;  sc = 0.125f * 1.44269504f; }
  else if (gid < 1179648) { s = wv; d = ywv; off = gid - 1048576; }
  else                    { s = wo; d = ywo; off = gid - 1179648; }
  const float* p = s + off * 8;
  float4 a = *(const float4*)p, b = *(const float4*)(p + 4);
  bf16x8 o;
  o[0] = (bf16_t)(a.x * sc); o[1] = (bf16_t)(a.y * sc);
  o[2] = (bf16_t)(a.z * sc); o[3] = (bf16_t)(a.w * sc);
  o[4] = (bf16_t)(b.x * sc); o[5] = (bf16_t)(b.y * sc);
  o[6] = (bf16_t)(b.z * sc); o[7] = (bf16_t)(b.w * sc);
  *(bf16x8*)(d + off * 8) = o;
}

// ---------------- GEMM core: 128x64 tile, BK=64, NT, all-bf16 (R8 verbatim) -
__device__ __forceinline__ void gemm_core(const bf16_t* __restrict__ A,
                                          const bf16_t* __restrict__ W,
                                          int bm, int bn,
                                          bf16_t (&As)[2][128 * 64],
                                          bf16_t (&Bs)[2][64 * 64],
                                          f32x4 (&acc)[4][2])
{
  const int tid = threadIdx.x, lane = tid & 63, wave = tid >> 6;
  const int l15 = lane & 15, l4 = lane >> 4, l7 = l15 & 7;
  const int wm = (wave >> 1) * 64, wn = (wave & 1) * 32;

  auto stage = [&](int buf, int k0) {
#pragma unroll
    for (int i = 0; i < 4; ++i) {
      const int id = i * 256 + tid, row = id >> 3, cph = id & 7;
      GLL16(A + (size_t)(bm + row) * 1024 + k0 + 8 * (cph ^ (row & 7)),
            &As[buf][(i * 256 + wave * 64) * 8]);
    }
#pragma unroll
    for (int i = 0; i < 2; ++i) {
      const int id = i * 256 + tid, row = id >> 3, cph = id & 7;
      GLL16(W + (size_t)(bn + row) * 1024 + k0 + 8 * (cph ^ (row & 7)),
            &Bs[buf][(i * 256 + wave * 64) * 8]);
    }
  };

  stage(0, 0);
#pragma unroll
  for (int s = 0; s < 16; ++s) {
    if (s + 1 < 16) stage((s + 1) & 1, (s + 1) * 64);
    __syncthreads();                       // buf[s&1] staged
    const bf16_t* as = As[s & 1];
    const bf16_t* bs = Bs[s & 1];
#pragma unroll
    for (int ks = 0; ks < 2; ++ks) {
      bf16x8 af[4], bfr[2];
#pragma unroll
      for (int i = 0; i < 4; ++i)
        af[i] = *(const bf16x8*)(&as[(wm + i * 16 + l15) * 64 + 8 * ((ks * 4 + l4) ^ l7)]);
#pragma unroll
      for (int j = 0; j < 2; ++j)
        bfr[j] = *(const bf16x8*)(&bs[(wn + j * 16 + l15) * 64 + 8 * ((ks * 4 + l4) ^ l7)]);
#pragma unroll
      for (int i = 0; i < 4; ++i)
#pragma unroll
        for (int j = 0; j < 2; ++j)
          acc[i][j] = MFMA(af[i], bfr[j], acc[i][j]);
    }
    __syncthreads();
  }
}

__global__ __launch_bounds__(256) void gemm_qkv(
    const bf16_t* __restrict__ xq, const bf16_t* __restrict__ xk, const bf16_t* __restrict__ xv,
    const bf16_t* __restrict__ ywq, const bf16_t* __restrict__ ywk, const bf16_t* __restrict__ ywv,
    bf16_t* __restrict__ qo, bf16_t* __restrict__ ko, bf16_t* __restrict__ vt)
{
  __shared__ __align__(16) bf16_t As[2][128 * 64];
  __shared__ __align__(16) bf16_t Bs[2][64 * 64];
  const int z = blockIdx.z;
  const bf16_t* A = z == 0 ? xq : z == 1 ? xk : xv;
  const bf16_t* W = z == 0 ? ywq : z == 1 ? ywk : ywv;
  const int bm = blockIdx.x * 128, bn = blockIdx.y * 64;
  f32x4 acc[4][2] = {};
  gemm_core(A, W, bm, bn, As, Bs, acc);
  const int tid = threadIdx.x, lane = tid & 63, wave = tid >> 6;
  const int l15 = lane & 15, l4 = lane >> 4;
  const int wm = (wave >> 1) * 64, wn = (wave & 1) * 32;
  if (z < 2) {
    bf16_t* C = z == 0 ? qo : ko;
#pragma unroll
    for (int i = 0; i < 4; ++i)
#pragma unroll
      for (int j = 0; j < 2; ++j)
#pragma unroll
        for (int r = 0; r < 4; ++r)
          C[(size_t)(bm + wm + i * 16 + 4 * l4 + r) * 1024 + bn + wn + j * 16 + l15] =
              (bf16_t)acc[i][j][r];
  } else {
#pragma unroll
    for (int i = 0; i < 4; ++i)
#pragma unroll
      for (int j = 0; j < 2; ++j)
#pragma unroll
        for (int r = 0; r < 4; ++r)
          vt[(size_t)(bn + wn + j * 16 + l15) * 2048 + bm + wm + i * 16 + 4 * l4 + r] =
              (bf16_t)acc[i][j][r];
  }
}

__global__ __launch_bounds__(256) void gemm_out(
    const bf16_t* __restrict__ ctx, const bf16_t* __restrict__ ywo, float* __restrict__ out)
{
  __shared__ __align__(16) bf16_t As[2][128 * 64];
  __shared__ __align__(16) bf16_t Bs[2][64 * 64];
  const int bm = blockIdx.x * 128, bn = blockIdx.y * 64;
  f32x4 acc[4][2] = {};
  gemm_core(ctx, ywo, bm, bn, As, Bs, acc);
  const int tid = threadIdx.x, lane = tid & 63, wave = tid >> 6;
  const int l15 = lane & 15, l4 = lane >> 4;
  const int wm = (wave >> 1) * 64, wn = (wave & 1) * 32;
#pragma unroll
  for (int i = 0; i < 4; ++i)
#pragma unroll
    for (int j = 0; j < 2; ++j)
#pragma unroll
      for (int r = 0; r < 4; ++r)
        out[(size_t)(bm + wm + i * 16 + 4 * l4 + r) * 1024 + bn + wn + j * 16 + l15] =
            acc[i][j][r];
}

// -------- attention: R8's attn1024 + exp2 (log2e pre-folded) + setprio ------
__global__ __launch_bounds__(1024) void attn1024(
    const bf16_t* __restrict__ Qb, const bf16_t* __restrict__ Kb,
    const bf16_t* __restrict__ Vt, bf16_t* __restrict__ Ctx)
{
  __shared__ __align__(16) char pool[64 * 1024 + 16 * 16 * 40 * 2 + 3 * 64 * 4];
  bf16_t* KsP = (bf16_t*)pool;                       // [2][128*64] swizzled
  bf16_t* VsP = (bf16_t*)(pool + 32 * 1024);         // [2][64*128] swizzled
  bf16_t* PsP = (bf16_t*)(pool + 64 * 1024);         // [16][16*40]
  float*  Osc = (float*)pool;                        // [3][64][66] combine
  float*  Dsc = (float*)(pool + 64 * 1024 + 16 * 16 * 40 * 2);  // [3][64]

  const int bid = blockIdx.x;
  const int h = 2 * (bid & 7) + (bid >> 7);          // head; 2 heads per XCD
  const int jp = (bid >> 3) & 15;
  const int hoff = h * 64;
  const int tid = threadIdx.x, lane = tid & 63, wave = tid >> 6;   // wave 0..15
  const int qg = wave & 3, kh = wave >> 2;           // q-group, key-quarter
  const int l15 = lane & 15, l4 = lane >> 4, l7 = l15 & 7;

  const int qtA = jp, qtB = 31 - jp;
  const int qbA = qtA * 64, qbB = qtB * 64;
  const int nscB = qtB / 2 + 1;                      // block-uniform loop count
  const int qmaxA = qbA + 16 * qg + 15;
  const int qmaxB = qbB + 16 * qg + 15;

  bf16x8 qA[2], qB[2];
#pragma unroll
  for (int kc = 0; kc < 2; ++kc) {
    qA[kc] = *(const bf16x8*)(Qb + (size_t)(qbA + 16 * qg + l15) * 1024 + hoff + 32 * kc + 8 * l4);
    qB[kc] = *(const bf16x8*)(Qb + (size_t)(qbB + 16 * qg + l15) * 1024 + hoff + 32 * kc + 8 * l4);
  }

  f32x4 oA[4] = {}, oB[4] = {};
  float dA[4] = {0.f, 0.f, 0.f, 0.f}, dB[4] = {0.f, 0.f, 0.f, 0.f};

  bf16x8 rk, rv;                                     // 1 K + 1 V chunk per thread
  auto issue = [&](int sc) {
    const int t0 = sc * 128;
    const int kr = tid >> 3, kc = tid & 7;
    rk = *(const bf16x8*)(Kb + (size_t)(t0 + kr) * 1024 + hoff + 8 * kc);
    const int vr = tid >> 4, vc = tid & 15;
    rv = *(const bf16x8*)(Vt + (size_t)(hoff + vr) * 2048 + t0 + 8 * vc);
  };
  auto commit = [&](int buf) {
    const int kr = tid >> 3, kc = tid & 7;
    *(bf16x8*)(&KsP[buf * 8192 + kr * 64 + 8 * (kc ^ (kr & 7))]) = rk;
    const int vr = tid >> 4, vc = tid & 15;
    *(bf16x8*)(&VsP[buf * 8192 + vr * 128 + 8 * (vc ^ (vr & 7))]) = rv;
  };

  bf16_t* Pw = &PsP[wave * 640];
  auto PROC1 = [&](int cur, int sc, int qb, int qmax, const bf16x8 (&qf)[2],
                   f32x4 (&oacc)[4], float (&den)[4]) {
    const int tb = sc * 128 + kh * 32;
    if (tb > qmax) return;                           // wave-uniform skip
    const bf16_t* Ksb = KsP + cur * 8192;
    const bf16_t* Vsb = VsP + cur * 8192;
    f32x4 sv[2] = {};
#pragma unroll
    for (int tf = 0; tf < 2; ++tf) {
      const int krow = 32 * kh + 16 * tf + l15;
      bf16x8 kf0 = *(const bf16x8*)(&Ksb[krow * 64 + 8 * (l4 ^ l7)]);
      bf16x8 kf1 = *(const bf16x8*)(&Ksb[krow * 64 + 8 * ((4 + l4) ^ l7)]);
      __builtin_amdgcn_s_setprio(1);
      sv[tf] = MFMA(qf[0], kf0, sv[tf]);
      sv[tf] = MFMA(qf[1], kf1, sv[tf]);
      __builtin_amdgcn_s_setprio(0);
    }
#pragma unroll
    for (int tf = 0; tf < 2; ++tf) {
      const int t = tb + 16 * tf + l15;
#pragma unroll
      for (int r = 0; r < 4; ++r) {
        const int qq = qb + 16 * qg + 4 * l4 + r;
        const float p = (t <= qq) ? __builtin_amdgcn_exp2f(sv[tf][r]) : 0.0f;
        const bf16_t pb = (bf16_t)p;
        den[r] += (float)pb;
        Pw[(4 * l4 + r) * 40 + 16 * tf + l15] = pb;
      }
    }
    asm volatile("s_waitcnt lgkmcnt(0)" ::: "memory");  // own-wave P visible
    bf16x8 pa = *(const bf16x8*)(&Pw[l15 * 40 + 8 * l4]);
    __builtin_amdgcn_s_setprio(1);
#pragma unroll
    for (int df = 0; df < 4; ++df) {
      const int vrow = 16 * df + l15;
      bf16x8 vf = *(const bf16x8*)(&Vsb[vrow * 128 + 8 * ((4 * kh + l4) ^ l7)]);
      oacc[df] = MFMA(pa, vf, oacc[df]);
    }
    __builtin_amdgcn_s_setprio(0);
  };

  issue(0);
  commit(0);
  int cur = 0;
  for (int sc = 0; sc < nscB; ++sc) {
    const bool pre = (sc + 1 < nscB);
    if (pre) issue(sc + 1);            // loads in flight across the barrier
    __syncthreads();                   // buf[cur] staged for all waves
    PROC1(cur, sc, qbB, qmaxB, qB, oB, dB);
    PROC1(cur, sc, qbA, qmaxA, qA, oA, dA);
    if (pre) commit(cur ^ 1);
    cur ^= 1;
  }

#pragma unroll
  for (int r = 0; r < 4; ++r)
#pragma unroll
    for (int m = 1; m < 16; m <<= 1) {
      dA[r] += __shfl_xor(dA[r], m, 64);
      dB[r] += __shfl_xor(dB[r], m, 64);
    }

  auto combine = [&](int qb, f32x4 (&oacc)[4], float (&den)[4]) {
    __syncthreads();                   // staging/scratch free for reuse
    if (kh > 0) {
      const int rl = qg * 16 + 4 * l4;
#pragma unroll
      for (int r = 0; r < 4; ++r) {
#pragma unroll
        for (int df = 0; df < 4; ++df)
          Osc[((kh - 1) * 64 + rl + r) * 66 + 16 * df + l15] = oacc[df][r];
        if (l15 == 0) Dsc[(kh - 1) * 64 + rl + r] = den[r];
      }
    }
    __syncthreads();
    if (kh == 0) {
#pragma unroll
      for (int r = 0; r < 4; ++r) {
        const int row = qg * 16 + 4 * l4 + r;
        const float dt = den[r] + Dsc[row] + Dsc[64 + row] + Dsc[128 + row];
        const float inv = 1.0f / dt;
#pragma unroll
        for (int df = 0; df < 4; ++df) {
          const int col = 16 * df + l15;
          const float s = oacc[df][r] + Osc[row * 66 + col] +
                          Osc[(64 + row) * 66 + col] + Osc[(128 + row) * 66 + col];
          Ctx[(size_t)(qb + row) * 1024 + hoff + col] = (bf16_t)(s * inv);
        }
      }
    }
  };
  combine(qbA, oA, dA);
  combine(qbB, oB, dB);
}

extern "C" void kernel_launch(void* const* d_in, const int* in_sizes, int n_in,
                              void* d_out, int out_size, void* d_ws, size_t ws_size,
                              hipStream_t stream)
{
  const float* query = (const float*)d_in[0];
  const float* key_  = (const float*)d_in[1];
  const float* value = (const float*)d_in[2];
  // d_in[3] = mask: exactly causal tril, reproduced from indices
  const float* Wq = (const float*)d_in[4];
  const float* Wk = (const float*)d_in[5];
  const float* Wv = (const float*)d_in[6];
  const float* Wo = (const float*)d_in[7];
  float* out = (float*)d_out;

  const size_t SE = (size_t)2048 * 1024, EE = (size_t)1024 * 1024;
  bf16_t* xq  = (bf16_t*)d_ws;      // converted activations (bf16)
  bf16_t* xk  = xq + SE;
  bf16_t* xv  = xk + SE;
  bf16_t* wq  = xv + SE;            // converted weights (scales folded)
  bf16_t* wk  = wq + EE;
  bf16_t* wv  = wk + EE;
  bf16_t* wo  = wv + EE;
  bf16_t* qo  = wo + EE;            // projections
  bf16_t* ko  = qo + SE;
  bf16_t* vt  = ko + SE;            // V transposed [1024][2048]
  bf16_t* ctx = vt + SE;            // attention output

  cvt_all<<<5120, 256, 0, stream>>>(query, key_, value, Wq, Wk, Wv, Wo,
                                    xq, xk, xv, wq, wk, wv, wo);
  gemm_qkv<<<dim3(16, 16, 3), 256, 0, stream>>>(xq, xk, xv, wq, wk, wv, qo, ko, vt);
  attn1024<<<256, 1024, 0, stream>>>(qo, ko, vt, ctx);
  gemm_out<<<dim3(16, 16), 256, 0, stream>>>(ctx, wo, out);
}